// Round 1
// baseline (4109.796 us; speedup 1.0000x reference)
//
#include <hip/hip_runtime.h>
#include <math.h>

#define N_NODES_ 50000
#define N_EDGES_ 1000000
#define HID 128
#define NG 50
#define NF 128
#define NCOL 4
#define TILE_E 32

// shifted softplus, matches jax.nn.softplus(v) - log(2) (stable form)
__device__ __forceinline__ float sspf(float v) {
    return fmaxf(v, 0.0f) + log1pf(expf(-fabsf(v))) - 0.69314718055994531f;
}

__device__ __forceinline__ void fma_2x8(float (&acc)[2][8], float2 a, float4 b0, float4 b1) {
    acc[0][0] += a.x * b0.x; acc[0][1] += a.x * b0.y;
    acc[0][2] += a.x * b0.z; acc[0][3] += a.x * b0.w;
    acc[0][4] += a.x * b1.x; acc[0][5] += a.x * b1.y;
    acc[0][6] += a.x * b1.z; acc[0][7] += a.x * b1.w;
    acc[1][0] += a.y * b0.x; acc[1][1] += a.y * b0.y;
    acc[1][2] += a.y * b0.z; acc[1][3] += a.y * b0.w;
    acc[1][4] += a.y * b1.x; acc[1][5] += a.y * b1.y;
    acc[1][6] += a.y * b1.z; acc[1][7] += a.y * b1.w;
}

// load 32-k-chunk of a [128][128] row-major weight, transposed into wT[k_local][col]
__device__ __forceinline__ void load_wT32(const float4* __restrict__ w4, int kc,
                                          float (*wT)[132], int tid) {
#pragma unroll
    for (int i = 0; i < 4; ++i) {
        int lin = tid + 256 * i;      // 0..1023
        int col = lin >> 3;           // 0..127
        int m = lin & 7;              // 0..7 -> k_local 4m..4m+3
        float4 v = w4[col * 32 + (kc >> 2) + m];
        wT[4 * m + 0][col] = v.x;
        wT[4 * m + 1][col] = v.y;
        wT[4 * m + 2][col] = v.z;
        wT[4 * m + 3][col] = v.w;
    }
}

// ---------------- bucket edges by color (LDS-aggregated counting scatter) -------------
__global__ __launch_bounds__(256) void bucket_kernel(const int* __restrict__ colors,
                                                     int* __restrict__ perm,
                                                     int* __restrict__ cnt) {
    __shared__ int lcnt[NCOL];
    __shared__ int lbase[NCOL];
    int tid = threadIdx.x;
    int e = blockIdx.x * 256 + tid;
    if (tid < NCOL) lcnt[tid] = 0;
    __syncthreads();
    int c = 0, rank = 0;
    if (e < N_EDGES_) {
        c = colors[e];
        rank = atomicAdd(&lcnt[c], 1);
    }
    __syncthreads();
    if (tid < NCOL) lbase[tid] = atomicAdd(&cnt[tid], lcnt[tid]);
    __syncthreads();
    if (e < N_EDGES_) perm[c * N_EDGES_ + lbase[c] + rank] = e;
}

// ---------------- h = x @ lin1_w^T  (50000x128 @ 128x128) ----------------
__global__ __launch_bounds__(256) void lin1_kernel(const float* __restrict__ x,
                                                   const float* __restrict__ w,
                                                   float* __restrict__ h) {
    __shared__ float xT[HID][36];   // [k][row], 32 rows per block
    __shared__ float wT[32][132];   // [k_local][col]
    int tid = threadIdx.x;
    int tx = tid & 15, ty = tid >> 4;
    int r0 = blockIdx.x * 32;
    const float4* x4 = (const float4*)x;
#pragma unroll
    for (int i = 0; i < 4; ++i) {
        int lin = tid + 256 * i;
        int r = lin >> 5, m = lin & 31;
        int rr = r0 + r; if (rr > N_NODES_ - 1) rr = N_NODES_ - 1;
        float4 v = x4[rr * 32 + m];
        xT[4 * m + 0][r] = v.x; xT[4 * m + 1][r] = v.y;
        xT[4 * m + 2][r] = v.z; xT[4 * m + 3][r] = v.w;
    }
    float acc[2][8] = {};
    for (int kc = 0; kc < HID; kc += 32) {
        __syncthreads();
        load_wT32((const float4*)w, kc, wT, tid);
        __syncthreads();
#pragma unroll 8
        for (int k2 = 0; k2 < 32; ++k2) {
            float2 a = *(const float2*)&xT[kc + k2][2 * ty];
            float4 b0 = *(const float4*)&wT[k2][8 * tx];
            float4 b1 = *(const float4*)&wT[k2][8 * tx + 4];
            fma_2x8(acc, a, b0, b1);
        }
    }
    float4* h4 = (float4*)h;
#pragma unroll
    for (int i = 0; i < 2; ++i) {
        int row = r0 + 2 * ty + i;
        if (row < N_NODES_) {
            h4[row * 32 + 2 * tx]     = make_float4(acc[i][0], acc[i][1], acc[i][2], acc[i][3]);
            h4[row * 32 + 2 * tx + 1] = make_float4(acc[i][4], acc[i][5], acc[i][6], acc[i][7]);
        }
    }
}

// ---------------- fused per-edge colored MLP + cutoff + gather + scatter-add ----------
__global__ __launch_bounds__(256) void edge_kernel(
    const int* __restrict__ edge_index, const float* __restrict__ edge_weight,
    const float* __restrict__ edge_attr,
    const float* __restrict__ m1w, const float* __restrict__ m1b,
    const float* __restrict__ m2w, const float* __restrict__ m2b,
    const float* __restrict__ h, const int* __restrict__ perm,
    const int* __restrict__ cnt, float* __restrict__ agg) {
    const int tiles = (N_EDGES_ + TILE_E - 1) / TILE_E;
    int c = blockIdx.x / tiles;
    int tile = blockIdx.x - c * tiles;
    int cntc = cnt[c];
    int t0 = tile * TILE_E;
    if (t0 >= cntc) return;
    int ne = min(TILE_E, cntc - t0);

    __shared__ float eaT[NG][TILE_E + 4];   // [k][edge]
    __shared__ float w1T[NG][132];          // [k][col]; aliased as m2 chunk buf in phase 2
    __shared__ float tsT[TILE_E][132];      // [edge][filt] hidden activations
    __shared__ int s_src[TILE_E], s_dst[TILE_E], s_eidx[TILE_E];
    __shared__ float s_cw[TILE_E];

    int tid = threadIdx.x;
    int tx = tid & 15, ty = tid >> 4;

    if (tid < TILE_E) {
        int r = tid;
        int idx = perm[c * N_EDGES_ + t0 + ((r < ne) ? r : 0)];
        s_eidx[r] = idx;
        if (r < ne) {
            s_src[r] = edge_index[idx];
            s_dst[r] = edge_index[N_EDGES_ + idx];
            float ww = edge_weight[idx];
            s_cw[r] = 0.5f * (cosf(ww * 0.31415926535897932f) + 1.0f);  // pi/CUTOFF
        }
    }
    __syncthreads();
    const float* m1 = m1w + c * (NF * NG);
    for (int lin = tid; lin < NF * NG; lin += 256) {
        int col = lin / NG;
        int k = lin - col * NG;
        w1T[k][col] = m1[lin];
    }
    for (int lin = tid; lin < TILE_E * NG; lin += 256) {
        int r = lin / NG;
        int k = lin - r * NG;
        eaT[k][r] = edge_attr[s_eidx[r] * NG + k];
    }
    __syncthreads();

    // phase 1: t = ssp(ea @ m1^T + b1)   [32 x 128], K=50
    float acc[2][8] = {};
    for (int k = 0; k < NG; ++k) {
        float2 a = *(const float2*)&eaT[k][2 * ty];
        float4 b0 = *(const float4*)&w1T[k][8 * tx];
        float4 b1 = *(const float4*)&w1T[k][8 * tx + 4];
        fma_2x8(acc, a, b0, b1);
    }
    const float* b1p = m1b + c * NF;
    {
        float v0[8], v1[8];
#pragma unroll
        for (int j = 0; j < 8; ++j) {
            float bb = b1p[8 * tx + j];
            v0[j] = sspf(acc[0][j] + bb);
            v1[j] = sspf(acc[1][j] + bb);
        }
        *(float4*)&tsT[2 * ty][8 * tx]         = make_float4(v0[0], v0[1], v0[2], v0[3]);
        *(float4*)&tsT[2 * ty][8 * tx + 4]     = make_float4(v0[4], v0[5], v0[6], v0[7]);
        *(float4*)&tsT[2 * ty + 1][8 * tx]     = make_float4(v1[0], v1[1], v1[2], v1[3]);
        *(float4*)&tsT[2 * ty + 1][8 * tx + 4] = make_float4(v1[4], v1[5], v1[6], v1[7]);
    }
    __syncthreads();

    // phase 2: u = t @ m2^T   [32 x 128], K=128, m2 streamed in 16-k chunks
    float acc2[2][8] = {};
    float* w2T = &w1T[0][0];   // [16][132] chunk buffer aliased onto w1T
    const float4* m2_4 = (const float4*)(m2w + c * (NF * NF));
    for (int kc = 0; kc < NF; kc += 16) {
#pragma unroll
        for (int i = 0; i < 2; ++i) {
            int lin = tid + 256 * i;   // 0..511
            int col = lin >> 2;        // 0..127
            int m = lin & 3;           // k_local 4m..4m+3
            float4 v = m2_4[col * 32 + (kc >> 2) + m];
            w2T[(4 * m + 0) * 132 + col] = v.x;
            w2T[(4 * m + 1) * 132 + col] = v.y;
            w2T[(4 * m + 2) * 132 + col] = v.z;
            w2T[(4 * m + 3) * 132 + col] = v.w;
        }
        __syncthreads();
#pragma unroll
        for (int k2 = 0; k2 < 16; ++k2) {
            float2 a = make_float2(tsT[2 * ty][kc + k2], tsT[2 * ty + 1][kc + k2]);
            float4 b0 = *(const float4*)&w2T[k2 * 132 + 8 * tx];
            float4 b1 = *(const float4*)&w2T[k2 * 132 + 8 * tx + 4];
            fma_2x8(acc2, a, b0, b1);
        }
        __syncthreads();
    }

    // epilogue: W = (u + b2) * C[e]; msg = h[src] .* W; agg[dst] += msg
    const float* b2p = m2b + c * NF;
    float bb[8];
#pragma unroll
    for (int j = 0; j < 8; ++j) bb[j] = b2p[8 * tx + j];
#pragma unroll
    for (int i = 0; i < 2; ++i) {
        int r = 2 * ty + i;
        if (r >= ne) continue;
        int s = s_src[r], d = s_dst[r];
        float cw = s_cw[r];
        const float4* hrow = (const float4*)(h + s * HID);
        float4 h0 = hrow[2 * tx], h1 = hrow[2 * tx + 1];
        float* arow = agg + d * HID + 8 * tx;
        atomicAdd(&arow[0], (acc2[i][0] + bb[0]) * cw * h0.x);
        atomicAdd(&arow[1], (acc2[i][1] + bb[1]) * cw * h0.y);
        atomicAdd(&arow[2], (acc2[i][2] + bb[2]) * cw * h0.z);
        atomicAdd(&arow[3], (acc2[i][3] + bb[3]) * cw * h0.w);
        atomicAdd(&arow[4], (acc2[i][4] + bb[4]) * cw * h1.x);
        atomicAdd(&arow[5], (acc2[i][5] + bb[5]) * cw * h1.y);
        atomicAdd(&arow[6], (acc2[i][6] + bb[6]) * cw * h1.z);
        atomicAdd(&arow[7], (acc2[i][7] + bb[7]) * cw * h1.w);
    }
}

// ---------------- out = ssp(agg @ lin2^T + b2) @ lin^T + b ----------------
__global__ __launch_bounds__(256) void out_kernel(
    const float* __restrict__ agg,
    const float* __restrict__ w2, const float* __restrict__ b2,
    const float* __restrict__ w3, const float* __restrict__ b3,
    float* __restrict__ out) {
    __shared__ float sT[HID][36];   // stage-A input transposed; then v transposed
    __shared__ float wT[32][132];
    int tid = threadIdx.x;
    int tx = tid & 15, ty = tid >> 4;
    int r0 = blockIdx.x * 32;
    const float4* a4 = (const float4*)agg;
#pragma unroll
    for (int i = 0; i < 4; ++i) {
        int lin = tid + 256 * i;
        int r = lin >> 5, m = lin & 31;
        int rr = r0 + r; if (rr > N_NODES_ - 1) rr = N_NODES_ - 1;
        float4 v = a4[rr * 32 + m];
        sT[4 * m + 0][r] = v.x; sT[4 * m + 1][r] = v.y;
        sT[4 * m + 2][r] = v.z; sT[4 * m + 3][r] = v.w;
    }
    float acc[2][8] = {};
    for (int kc = 0; kc < HID; kc += 32) {
        __syncthreads();
        load_wT32((const float4*)w2, kc, wT, tid);
        __syncthreads();
#pragma unroll 8
        for (int k2 = 0; k2 < 32; ++k2) {
            float2 a = *(const float2*)&sT[kc + k2][2 * ty];
            float4 c0 = *(const float4*)&wT[k2][8 * tx];
            float4 c1 = *(const float4*)&wT[k2][8 * tx + 4];
            fma_2x8(acc, a, c0, c1);
        }
    }
    __syncthreads();   // all stage-A reads of sT done before overwrite
#pragma unroll
    for (int j = 0; j < 8; ++j) {
        int col = 8 * tx + j;
        float bbv = b2[col];
        sT[col][2 * ty]     = sspf(acc[0][j] + bbv);
        sT[col][2 * ty + 1] = sspf(acc[1][j] + bbv);
    }
    float acc2[2][8] = {};
    for (int kc = 0; kc < HID; kc += 32) {
        __syncthreads();
        load_wT32((const float4*)w3, kc, wT, tid);
        __syncthreads();
#pragma unroll 8
        for (int k2 = 0; k2 < 32; ++k2) {
            float2 a = *(const float2*)&sT[kc + k2][2 * ty];
            float4 c0 = *(const float4*)&wT[k2][8 * tx];
            float4 c1 = *(const float4*)&wT[k2][8 * tx + 4];
            fma_2x8(acc2, a, c0, c1);
        }
    }
    float4* out4 = (float4*)out;
#pragma unroll
    for (int i = 0; i < 2; ++i) {
        int row = r0 + 2 * ty + i;
        if (row < N_NODES_) {
            out4[row * 32 + 2 * tx] = make_float4(
                acc2[i][0] + b3[8 * tx + 0], acc2[i][1] + b3[8 * tx + 1],
                acc2[i][2] + b3[8 * tx + 2], acc2[i][3] + b3[8 * tx + 3]);
            out4[row * 32 + 2 * tx + 1] = make_float4(
                acc2[i][4] + b3[8 * tx + 4], acc2[i][5] + b3[8 * tx + 5],
                acc2[i][6] + b3[8 * tx + 6], acc2[i][7] + b3[8 * tx + 7]);
        }
    }
}

extern "C" void kernel_launch(void* const* d_in, const int* in_sizes, int n_in,
                              void* d_out, int out_size, void* d_ws, size_t ws_size,
                              hipStream_t stream) {
    const float* x           = (const float*)d_in[0];
    const int*   edge_index  = (const int*)d_in[1];
    const float* edge_weight = (const float*)d_in[2];
    const float* edge_attr   = (const float*)d_in[3];
    const int*   colors      = (const int*)d_in[4];
    const float* m1w         = (const float*)d_in[5];
    const float* m1b         = (const float*)d_in[6];
    const float* m2w         = (const float*)d_in[7];
    const float* m2b         = (const float*)d_in[8];
    const float* lin1w       = (const float*)d_in[9];
    const float* lin2w       = (const float*)d_in[10];
    const float* lin2b       = (const float*)d_in[11];
    const float* linw        = (const float*)d_in[12];
    const float* linb        = (const float*)d_in[13];
    float* out = (float*)d_out;

    // workspace layout (bytes): h 25.6M | agg 25.6M | perm 16M | cnt 64B
    char* ws = (char*)d_ws;
    float* h   = (float*)(ws);
    float* agg = (float*)(ws + 25600000);
    int*   perm = (int*)(ws + 51200000);
    int*   cnt  = (int*)(ws + 67200000);

    hipMemsetAsync(agg, 0, (size_t)N_NODES_ * HID * sizeof(float), stream);
    hipMemsetAsync(cnt, 0, NCOL * sizeof(int), stream);

    bucket_kernel<<<(N_EDGES_ + 255) / 256, 256, 0, stream>>>(colors, perm, cnt);
    lin1_kernel<<<(N_NODES_ + 31) / 32, 256, 0, stream>>>(x, lin1w, h);
    const int tiles = (N_EDGES_ + TILE_E - 1) / TILE_E;
    edge_kernel<<<NCOL * tiles, 256, 0, stream>>>(edge_index, edge_weight, edge_attr,
                                                  m1w, m1b, m2w, m2b, h, perm, cnt, agg);
    out_kernel<<<(N_NODES_ + 31) / 32, 256, 0, stream>>>(agg, lin2w, lin2b, linw, linb, out);
}

// Round 2
// 1954.738 us; speedup vs baseline: 2.1025x; 2.1025x over previous
//
#include <hip/hip_runtime.h>
#include <math.h>

#define N_NODES_ 50000
#define N_EDGES_ 1000000
#define HID 128
#define NG 50
#define NF 128
#define NCOL 4
#define CSEG 258048            // 64-aligned per-color capacity (>> 250K + 18 sigma)
#define NKEY (NCOL * N_NODES_) // 200000
#define CHUNK 625              // 50000 = 80 * 625
#define NCHUNK_PER_C 80
#define NCHUNK (NCOL * NCHUNK_PER_C)

typedef short s16x8 __attribute__((ext_vector_type(8)));
typedef float f32x4 __attribute__((ext_vector_type(4)));

__device__ __forceinline__ float sspf(float v) {
    // log(1+e^v) - log2, fast-math; for large v avoid inf
    float r = __logf(1.f + __expf(v)) - 0.69314718055994531f;
    return (v > 15.f) ? (v - 0.69314718055994531f) : r;
}

__device__ __forceinline__ unsigned int f2b(float f) {  // f32 -> bf16 (RNE), in low 16
    unsigned int u = __float_as_uint(f);
    return (u + 0x7fffu + ((u >> 16) & 1u)) >> 16;
}

// ---------------- histogram over (color,dst) keys ----------------
__global__ __launch_bounds__(256) void hist_kernel(const int* __restrict__ colors,
                                                   const int* __restrict__ edge_index,
                                                   int* __restrict__ hist) {
    int e = blockIdx.x * 256 + threadIdx.x;
    if (e < N_EDGES_) {
        int key = colors[e] * N_NODES_ + edge_index[N_EDGES_ + e];
        atomicAdd(&hist[key], 1);
    }
}

// ---------------- per-chunk exclusive scan (in place) ----------------
__global__ __launch_bounds__(256) void scan1_kernel(int* __restrict__ hist,
                                                    int* __restrict__ csum) {
    __shared__ int s[CHUNK];
    int b = blockIdx.x;                  // 0..319
    int c = b / NCHUNK_PER_C, ch = b % NCHUNK_PER_C;
    int gofs = c * N_NODES_ + ch * CHUNK;
    for (int i = threadIdx.x; i < CHUNK; i += 256) s[i] = hist[gofs + i];
    __syncthreads();
    if (threadIdx.x == 0) {
        int run = 0;
        for (int i = 0; i < CHUNK; ++i) { int t = s[i]; s[i] = run; run += t; }
        csum[b] = run;
    }
    __syncthreads();
    for (int i = threadIdx.x; i < CHUNK; i += 256) hist[gofs + i] = s[i];
}

__global__ __launch_bounds__(64) void scan2_kernel(const int* __restrict__ csum,
                                                   int* __restrict__ cbase,
                                                   int* __restrict__ g_cnt) {
    int c = threadIdx.x;
    if (c < NCOL) {
        int run = 0;
        for (int j = 0; j < NCHUNK_PER_C; ++j) {
            cbase[c * NCHUNK_PER_C + j] = run;
            run += csum[c * NCHUNK_PER_C + j];
        }
        g_cnt[c] = run;
    }
}

__global__ __launch_bounds__(256) void scan3_kernel(int* __restrict__ hist,
                                                    const int* __restrict__ cbase) {
    int b = blockIdx.x;
    int c = b / NCHUNK_PER_C, ch = b % NCHUNK_PER_C;
    int gofs = c * N_NODES_ + ch * CHUNK;
    int add = cbase[b];
    for (int i = threadIdx.x; i < CHUNK; i += 256) hist[gofs + i] += add;
}

// ---------------- scatter into (color,dst)-sorted order ----------------
__global__ __launch_bounds__(256) void scatter_kernel(const int* __restrict__ colors,
                                                      const int* __restrict__ edge_index,
                                                      int* __restrict__ base,  // = scanned hist (used as cursor)
                                                      int* __restrict__ eid_s) {
    int e = blockIdx.x * 256 + threadIdx.x;
    if (e < N_EDGES_) {
        int c = colors[e];
        int key = c * N_NODES_ + edge_index[N_EDGES_ + e];
        int r = atomicAdd(&base[key], 1);
        eid_s[c * CSEG + r] = e;
    }
}

// ---------------- convert MLP weights to bf16 (zero-padded K for m1) ----------------
__global__ __launch_bounds__(256) void wconv_kernel(const float* __restrict__ m1w,
                                                    const float* __restrict__ m2w,
                                                    unsigned short* __restrict__ m1b16,
                                                    unsigned short* __restrict__ m2b16) {
    int idx = blockIdx.x * 256 + threadIdx.x;
    if (idx < NCOL * NF * 64) {
        int c = idx / (NF * 64);
        int rem = idx % (NF * 64);
        int n = rem / 64, k = rem % 64;
        float v = (k < NG) ? m1w[(c * NF + n) * NG + k] : 0.f;
        m1b16[idx] = (unsigned short)f2b(v);
    } else if (idx < NCOL * NF * 64 + NCOL * NF * NF) {
        int j = idx - NCOL * NF * 64;
        m2b16[j] = (unsigned short)f2b(m2w[j]);
    }
}

// ---------------- fused edge pass: colored MLP (MFMA bf16) + cutoff + gather +
//                  in-tile dst-run reduction + atomic emit ----------------
__global__ __launch_bounds__(256, 2) void passA_kernel(
    const int* __restrict__ edge_index, const float* __restrict__ edge_weight,
    const float* __restrict__ edge_attr,
    const unsigned short* __restrict__ m1b16, const unsigned short* __restrict__ m2b16,
    const float* __restrict__ m1bias, const float* __restrict__ m2bias,
    const float* __restrict__ h, const int* __restrict__ eid_s,
    const int* __restrict__ g_cnt, float* __restrict__ agg) {

    __shared__ __align__(16) unsigned short eaT[64][80];   // [edge][k<=64 padded]
    __shared__ __align__(16) unsigned short tsT[64][144];  // [edge][filter]
    __shared__ __align__(16) float accL[64][132];          // [run][filter]
    __shared__ float bias1[NF], bias2[NF];
    __shared__ int s_src[64], s_dst[64], s_rdst[64];
    __shared__ float s_cw[64];
    __shared__ unsigned char s_u[64];
    __shared__ int s_nruns;

    int c = blockIdx.x >> 12;            // 4096 tiles per color
    int tile = blockIdx.x & 4095;
    int cnt = g_cnt[c];
    if (tile * 64 >= cnt) return;
    int pos0 = c * CSEG + tile * 64;

    int tid = threadIdx.x;
    int wv = tid >> 6;
    int l15 = tid & 15;
    int q = (tid >> 4) & 3;
    int e = (wv << 4) | l15;             // this thread's edge row in tile

    // zero run accumulator
    {
        f32x4* a4 = (f32x4*)&accL[0][0];
        for (int i = tid; i < 64 * 132 / 4; i += 256) a4[i] = (f32x4)(0.f);
    }
    if (tid < NF) bias1[tid] = m1bias[c * NF + tid];
    else          bias2[tid - NF] = m2bias[c * NF + tid - NF];

    // wave 0: per-edge meta + run ids
    if (tid < 64) {
        int eid = eid_s[pos0 + tid];
        int sidx = 0, d = -1;
        float cw = 0.f;
        if (eid >= 0) {
            sidx = edge_index[eid];
            d = edge_index[N_EDGES_ + eid];
            float ww = edge_weight[eid];
            cw = 0.5f * (__cosf(ww * 0.31415926535897932f) + 1.f);
        }
        s_src[tid] = sidx; s_dst[tid] = d; s_cw[tid] = cw;
        int prev = (tid == 0) ? (d ^ 1) : s_dst[tid - 1];
        bool isb = (d != prev);
        unsigned long long m = __ballot(isb);
        int u = __popcll(m & ((2ull << tid) - 1)) - 1;
        s_u[tid] = (unsigned char)u;
        if (isb) s_rdst[u] = d;
        if (tid == 63) s_nruns = u + 1;
    }

    // edge_attr -> bf16 LDS (zero pad k=50..79)
    {
        int r = tid >> 2, j0 = tid & 3;
        int eid = eid_s[pos0 + r];
        if (eid < 0) eid = 0;
        const float* ear = edge_attr + (size_t)eid * NG;
#pragma unroll
        for (int j = 0; j < 10; ++j) {
            int i2 = j0 + 4 * j;         // float2 index 0..39
            unsigned int pk = 0;
            if (i2 < 25) {
                float2 v = *(const float2*)(ear + 2 * i2);
                pk = f2b(v.x) | (f2b(v.y) << 16);
            }
            *(unsigned int*)&eaT[r][2 * i2] = pk;
        }
    }
    __syncthreads();

    // phase 1: t = ssp(m1 @ ea^T + b1)   D rows = filter, cols = edge
    f32x4 acc[8];
#pragma unroll
    for (int m = 0; m < 8; ++m) acc[m] = (f32x4)(0.f);
    {
        const unsigned short* m1p = m1b16 + (size_t)c * NF * 64;
#pragma unroll
        for (int ks = 0; ks < 2; ++ks) {
            s16x8 bfrag = *(const s16x8*)&eaT[e][q * 8 + 32 * ks];
#pragma unroll
            for (int m = 0; m < 8; ++m) {
                s16x8 afrag = *(const s16x8*)(m1p + (m * 16 + l15) * 64 + q * 8 + 32 * ks);
                acc[m] = __builtin_amdgcn_mfma_f32_16x16x32_bf16(afrag, bfrag, acc[m], 0, 0, 0);
            }
        }
    }
#pragma unroll
    for (int m = 0; m < 8; ++m) {
        int n0 = m * 16 + q * 4;
        float t0 = sspf(acc[m][0] + bias1[n0 + 0]);
        float t1 = sspf(acc[m][1] + bias1[n0 + 1]);
        float t2 = sspf(acc[m][2] + bias1[n0 + 2]);
        float t3 = sspf(acc[m][3] + bias1[n0 + 3]);
        unsigned int p0 = f2b(t0) | (f2b(t1) << 16);
        unsigned int p1 = f2b(t2) | (f2b(t3) << 16);
        uint2 pk; pk.x = p0; pk.y = p1;
        *(uint2*)&tsT[e][n0] = pk;       // same-wave rows: no barrier needed
    }

    // phase 2: u = m2 @ t^T   D rows = filter, cols = edge
    f32x4 acc2[8];
#pragma unroll
    for (int m = 0; m < 8; ++m) acc2[m] = (f32x4)(0.f);
    {
        const unsigned short* m2p = m2b16 + (size_t)c * NF * NF;
#pragma unroll
        for (int ks = 0; ks < 4; ++ks) {
            s16x8 bfrag = *(const s16x8*)&tsT[e][q * 8 + 32 * ks];
#pragma unroll
            for (int m = 0; m < 8; ++m) {
                s16x8 afrag = *(const s16x8*)(m2p + (m * 16 + l15) * NF + q * 8 + 32 * ks);
                acc2[m] = __builtin_amdgcn_mfma_f32_16x16x32_bf16(afrag, bfrag, acc2[m], 0, 0, 0);
            }
        }
    }

    // epilogue: msg = h[src] * (u + b2) * cw; reduce into run accumulator
    {
        int sdst = s_dst[e];
        if (sdst >= 0) {
            float cw = s_cw[e];
            int u = s_u[e];
            const float* hrow = h + (size_t)s_src[e] * HID;
#pragma unroll
            for (int m = 0; m < 8; ++m) {
                int n0 = m * 16 + q * 4;
                f32x4 hv = *(const f32x4*)(hrow + n0);
                float w0 = (acc2[m][0] + bias2[n0 + 0]) * cw;
                float w1 = (acc2[m][1] + bias2[n0 + 1]) * cw;
                float w2 = (acc2[m][2] + bias2[n0 + 2]) * cw;
                float w3 = (acc2[m][3] + bias2[n0 + 3]) * cw;
                atomicAdd(&accL[u][n0 + 0], w0 * hv[0]);
                atomicAdd(&accL[u][n0 + 1], w1 * hv[1]);
                atomicAdd(&accL[u][n0 + 2], w2 * hv[2]);
                atomicAdd(&accL[u][n0 + 3], w3 * hv[3]);
            }
        }
    }
    __syncthreads();

    // emit: one atomic row per run
    int nr = s_nruns;
    for (int idx = tid; idx < nr * 32; idx += 256) {
        int r = idx >> 5, c4 = (idx & 31) << 2;
        int d = s_rdst[r];
        if (d >= 0) {
            float* ap = agg + (size_t)d * HID + c4;
            f32x4 v = *(f32x4*)&accL[r][c4];
            atomicAdd(ap + 0, v[0]);
            atomicAdd(ap + 1, v[1]);
            atomicAdd(ap + 2, v[2]);
            atomicAdd(ap + 3, v[3]);
        }
    }
}

// ---------------- f32 helpers for lin1 / out (unchanged from round 1) ----------------
__device__ __forceinline__ void fma_2x8(float (&acc)[2][8], float2 a, float4 b0, float4 b1) {
    acc[0][0] += a.x * b0.x; acc[0][1] += a.x * b0.y;
    acc[0][2] += a.x * b0.z; acc[0][3] += a.x * b0.w;
    acc[0][4] += a.x * b1.x; acc[0][5] += a.x * b1.y;
    acc[0][6] += a.x * b1.z; acc[0][7] += a.x * b1.w;
    acc[1][0] += a.y * b0.x; acc[1][1] += a.y * b0.y;
    acc[1][2] += a.y * b0.z; acc[1][3] += a.y * b0.w;
    acc[1][4] += a.y * b1.x; acc[1][5] += a.y * b1.y;
    acc[1][6] += a.y * b1.z; acc[1][7] += a.y * b1.w;
}

__device__ __forceinline__ void load_wT32(const float4* __restrict__ w4, int kc,
                                          float (*wT)[132], int tid) {
#pragma unroll
    for (int i = 0; i < 4; ++i) {
        int lin = tid + 256 * i;
        int col = lin >> 3;
        int m = lin & 7;
        float4 v = w4[col * 32 + (kc >> 2) + m];
        wT[4 * m + 0][col] = v.x;
        wT[4 * m + 1][col] = v.y;
        wT[4 * m + 2][col] = v.z;
        wT[4 * m + 3][col] = v.w;
    }
}

__global__ __launch_bounds__(256) void lin1_kernel(const float* __restrict__ x,
                                                   const float* __restrict__ w,
                                                   float* __restrict__ h) {
    __shared__ float xT[HID][36];
    __shared__ float wT[32][132];
    int tid = threadIdx.x;
    int tx = tid & 15, ty = tid >> 4;
    int r0 = blockIdx.x * 32;
    const float4* x4 = (const float4*)x;
#pragma unroll
    for (int i = 0; i < 4; ++i) {
        int lin = tid + 256 * i;
        int r = lin >> 5, m = lin & 31;
        int rr = r0 + r; if (rr > N_NODES_ - 1) rr = N_NODES_ - 1;
        float4 v = x4[rr * 32 + m];
        xT[4 * m + 0][r] = v.x; xT[4 * m + 1][r] = v.y;
        xT[4 * m + 2][r] = v.z; xT[4 * m + 3][r] = v.w;
    }
    float acc[2][8] = {};
    for (int kc = 0; kc < HID; kc += 32) {
        __syncthreads();
        load_wT32((const float4*)w, kc, wT, tid);
        __syncthreads();
#pragma unroll 8
        for (int k2 = 0; k2 < 32; ++k2) {
            float2 a = *(const float2*)&xT[kc + k2][2 * ty];
            float4 b0 = *(const float4*)&wT[k2][8 * tx];
            float4 b1 = *(const float4*)&wT[k2][8 * tx + 4];
            fma_2x8(acc, a, b0, b1);
        }
    }
    float4* h4 = (float4*)h;
#pragma unroll
    for (int i = 0; i < 2; ++i) {
        int row = r0 + 2 * ty + i;
        if (row < N_NODES_) {
            h4[row * 32 + 2 * tx]     = make_float4(acc[i][0], acc[i][1], acc[i][2], acc[i][3]);
            h4[row * 32 + 2 * tx + 1] = make_float4(acc[i][4], acc[i][5], acc[i][6], acc[i][7]);
        }
    }
}

__global__ __launch_bounds__(256) void out_kernel(
    const float* __restrict__ agg,
    const float* __restrict__ w2, const float* __restrict__ b2,
    const float* __restrict__ w3, const float* __restrict__ b3,
    float* __restrict__ out) {
    __shared__ float sT[HID][36];
    __shared__ float wT[32][132];
    int tid = threadIdx.x;
    int tx = tid & 15, ty = tid >> 4;
    int r0 = blockIdx.x * 32;
    const float4* a4 = (const float4*)agg;
#pragma unroll
    for (int i = 0; i < 4; ++i) {
        int lin = tid + 256 * i;
        int r = lin >> 5, m = lin & 31;
        int rr = r0 + r; if (rr > N_NODES_ - 1) rr = N_NODES_ - 1;
        float4 v = a4[rr * 32 + m];
        sT[4 * m + 0][r] = v.x; sT[4 * m + 1][r] = v.y;
        sT[4 * m + 2][r] = v.z; sT[4 * m + 3][r] = v.w;
    }
    float acc[2][8] = {};
    for (int kc = 0; kc < HID; kc += 32) {
        __syncthreads();
        load_wT32((const float4*)w2, kc, wT, tid);
        __syncthreads();
#pragma unroll 8
        for (int k2 = 0; k2 < 32; ++k2) {
            float2 a = *(const float2*)&sT[kc + k2][2 * ty];
            float4 c0 = *(const float4*)&wT[k2][8 * tx];
            float4 c1 = *(const float4*)&wT[k2][8 * tx + 4];
            fma_2x8(acc, a, c0, c1);
        }
    }
    __syncthreads();
#pragma unroll
    for (int j = 0; j < 8; ++j) {
        int col = 8 * tx + j;
        float bbv = b2[col];
        sT[col][2 * ty]     = sspf(acc[0][j] + bbv);
        sT[col][2 * ty + 1] = sspf(acc[1][j] + bbv);
    }
    float acc2[2][8] = {};
    for (int kc = 0; kc < HID; kc += 32) {
        __syncthreads();
        load_wT32((const float4*)w3, kc, wT, tid);
        __syncthreads();
#pragma unroll 8
        for (int k2 = 0; k2 < 32; ++k2) {
            float2 a = *(const float2*)&sT[kc + k2][2 * ty];
            float4 c0 = *(const float4*)&wT[k2][8 * tx];
            float4 c1 = *(const float4*)&wT[k2][8 * tx + 4];
            fma_2x8(acc2, a, c0, c1);
        }
    }
    float4* out4 = (float4*)out;
#pragma unroll
    for (int i = 0; i < 2; ++i) {
        int row = r0 + 2 * ty + i;
        if (row < N_NODES_) {
            out4[row * 32 + 2 * tx] = make_float4(
                acc2[i][0] + b3[8 * tx + 0], acc2[i][1] + b3[8 * tx + 1],
                acc2[i][2] + b3[8 * tx + 2], acc2[i][3] + b3[8 * tx + 3]);
            out4[row * 32 + 2 * tx + 1] = make_float4(
                acc2[i][4] + b3[8 * tx + 4], acc2[i][5] + b3[8 * tx + 5],
                acc2[i][6] + b3[8 * tx + 6], acc2[i][7] + b3[8 * tx + 7]);
        }
    }
}

extern "C" void kernel_launch(void* const* d_in, const int* in_sizes, int n_in,
                              void* d_out, int out_size, void* d_ws, size_t ws_size,
                              hipStream_t stream) {
    const float* x           = (const float*)d_in[0];
    const int*   edge_index  = (const int*)d_in[1];
    const float* edge_weight = (const float*)d_in[2];
    const float* edge_attr   = (const float*)d_in[3];
    const int*   colors      = (const int*)d_in[4];
    const float* m1w         = (const float*)d_in[5];
    const float* m1b         = (const float*)d_in[6];
    const float* m2w         = (const float*)d_in[7];
    const float* m2b         = (const float*)d_in[8];
    const float* lin1w       = (const float*)d_in[9];
    const float* lin2w       = (const float*)d_in[10];
    const float* lin2b       = (const float*)d_in[11];
    const float* linw        = (const float*)d_in[12];
    const float* linb        = (const float*)d_in[13];
    float* out = (float*)d_out;

    // workspace layout (bytes)
    char* ws = (char*)d_ws;
    float* h      = (float*)(ws);                         // 25,600,000
    float* agg    = (float*)(ws + 25600000);              // 25,600,000
    int*   eid_s  = (int*)(ws + 51200000);                // 4*CSEG*4 = 4,128,768
    int*   base   = (int*)(ws + 55328768);                // NKEY*4 = 800,000
    int*   csum   = (int*)(ws + 56128768);                // 1,280
    int*   cbase  = (int*)(ws + 56130048);                // 1,280
    int*   g_cnt  = (int*)(ws + 56131328);                // 64
    unsigned short* m1b16 = (unsigned short*)(ws + 56131392);  // 65,536
    unsigned short* m2b16 = (unsigned short*)(ws + 56196928);  // 131,072
    // end ~56.33 MB (round 1 proved ws >= 67.2 MB)

    hipMemsetAsync(agg, 0, (size_t)N_NODES_ * HID * sizeof(float), stream);
    hipMemsetAsync(base, 0, NKEY * sizeof(int), stream);
    hipMemsetAsync(eid_s, 0xFF, (size_t)NCOL * CSEG * sizeof(int), stream);  // -1 pads

    hist_kernel<<<(N_EDGES_ + 255) / 256, 256, 0, stream>>>(colors, edge_index, base);
    scan1_kernel<<<NCHUNK, 256, 0, stream>>>(base, csum);
    scan2_kernel<<<1, 64, 0, stream>>>(csum, cbase, g_cnt);
    scan3_kernel<<<NCHUNK, 256, 0, stream>>>(base, cbase);
    scatter_kernel<<<(N_EDGES_ + 255) / 256, 256, 0, stream>>>(colors, edge_index, base, eid_s);
    wconv_kernel<<<(NCOL * NF * 64 + NCOL * NF * NF + 255) / 256, 256, 0, stream>>>(m1w, m2w, m1b16, m2b16);
    lin1_kernel<<<(N_NODES_ + 31) / 32, 256, 0, stream>>>(x, lin1w, h);
    passA_kernel<<<NCOL * 4096, 256, 0, stream>>>(edge_index, edge_weight, edge_attr,
                                                  m1b16, m2b16, m1b, m2b, h, eid_s, g_cnt, agg);
    out_kernel<<<(N_NODES_ + 31) / 32, 256, 0, stream>>>(agg, lin2w, lin2b, linw, linb, out);
}